// Round 1
// baseline (195.199 us; speedup 1.0000x reference)
//
#include <hip/hip_runtime.h>
#include <hip/hip_bf16.h>
#include <stdint.h>

// EncoderBlock: B=8, S=1024, D=512, H=12, HS=42 (padded to 64 for GEMM).
// Only batch 0's attention is used (reference quirk: attn[0] + x).

typedef unsigned short u16;
typedef __attribute__((ext_vector_type(8))) short short8;  // 8 bf16 = 4 VGPRs
typedef __attribute__((ext_vector_type(4))) float f32x4;

__device__ __forceinline__ u16 f2bf(float f) {
  union { float f; unsigned u; } x; x.f = f;
  return (u16)((x.u + 0x7FFFu + ((x.u >> 16) & 1u)) >> 16);  // RNE
}
__device__ __forceinline__ float bf2f(u16 u) {
  union { unsigned u; float f; } x; x.u = ((unsigned)u) << 16;
  return x.f;
}

// async global->LDS, 16B per lane; LDS dest is wave-uniform base + lane*16.
__device__ __forceinline__ void gload_lds16(const u16* g, u16* l) {
  __builtin_amdgcn_global_load_lds(
      (__attribute__((address_space(1))) void*)g,
      (__attribute__((address_space(3))) void*)l, 16, 0, 0);
}

__device__ __forceinline__ float wred_sum(float v) {
#pragma unroll
  for (int off = 32; off > 0; off >>= 1) v += __shfl_xor(v, off, 64);
  return v;
}
__device__ __forceinline__ float wred_max(float v) {
#pragma unroll
  for (int off = 32; off > 0; off >>= 1) v = fmaxf(v, __shfl_xor(v, off, 64));
  return v;
}

// ---------------------------------------------------------------------------
// GEMM: C[m][n] = sum_k A[m][k] * Bt[n][k]   (A,Bt bf16 row-major; Bt is B^T)
// 128x128 tile, BK=32, 4 waves (2x2), mfma_f32_16x16x32_bf16. m97 structure.
// Epilogues: 0=bf16 store, 1=PV (col<42, *invl, scatter to concat),
//            2=f32+bias, 3=gelu(x+bias)->bf16, 4=f32+bias+resid (final out)
// ---------------------------------------------------------------------------
enum { EP_BF16 = 0, EP_PV = 1, EP_F32B = 2, EP_GELU = 3, EP_OUT = 4 };

template <int EP>
__launch_bounds__(256, 2)
__global__ void gemm_bt(const u16* __restrict__ A, int lda, long sAz,
                        const u16* __restrict__ Bt, int ldb, long sBz,
                        void* __restrict__ Cv, int ldc, long sCz,
                        int K, const float* __restrict__ bias,
                        const float* __restrict__ aux) {
  __shared__ u16 lA[128 * 32];  // [m][k] linear, 8KB
  __shared__ u16 lB[128 * 32];  // [n][k] linear
  const int z = blockIdx.z;
  const u16* Ab = A + (long)z * sAz;
  const u16* Bb = Bt + (long)z * sBz;
  const int m0 = blockIdx.x * 128;
  const int n0 = blockIdx.y * 128;
  const int tid = threadIdx.x;
  const int w = tid >> 6;
  const int l = tid & 63;
  const int wr = w >> 1;
  const int wc = w & 1;

  f32x4 acc[4][4];
#pragma unroll
  for (int i = 0; i < 4; ++i)
#pragma unroll
    for (int j = 0; j < 4; ++j) acc[i][j] = (f32x4){0.f, 0.f, 0.f, 0.f};

  // staging: wave w covers tile rows [w*32, w*32+32), 2 instrs of 1KB each
  const int sm = w * 32 + (l >> 2);
  const int sk = (l & 3) * 8;
  const u16* ga0 = Ab + (long)(m0 + sm) * lda + sk;
  const u16* ga1 = Ab + (long)(m0 + sm + 16) * lda + sk;
  const u16* gb0 = Bb + (long)(n0 + sm) * ldb + sk;
  const u16* gb1 = Bb + (long)(n0 + sm + 16) * ldb + sk;
  u16* dA = &lA[w * 1024];
  u16* dB = &lB[w * 1024];

  // fragment read offsets: A row = l&15, k = (l>>4)*8 (+8 contiguous)
  const int aoff = (wr * 64 + (l & 15)) * 32 + (l >> 4) * 8;
  const int boff = (wc * 64 + (l & 15)) * 32 + (l >> 4) * 8;

  for (int k0 = 0; k0 < K; k0 += 32) {
    gload_lds16(ga0 + k0, dA);
    gload_lds16(ga1 + k0, dA + 512);
    gload_lds16(gb0 + k0, dB);
    gload_lds16(gb1 + k0, dB + 512);
    __syncthreads();
    short8 af[4], bfv[4];
#pragma unroll
    for (int mi = 0; mi < 4; ++mi)
      af[mi] = *(const short8*)&lA[aoff + mi * 16 * 32];
#pragma unroll
    for (int ni = 0; ni < 4; ++ni)
      bfv[ni] = *(const short8*)&lB[boff + ni * 16 * 32];
#pragma unroll
    for (int mi = 0; mi < 4; ++mi)
#pragma unroll
      for (int ni = 0; ni < 4; ++ni)
        acc[mi][ni] = __builtin_amdgcn_mfma_f32_16x16x32_bf16(
            af[mi], bfv[ni], acc[mi][ni], 0, 0, 0);
    __syncthreads();
  }

  // C/D mapping: col = lane&15, row = (lane>>4)*4 + reg  [m89-verified]
  const int rbase = m0 + wr * 64 + (l >> 4) * 4;
  const int cbase = n0 + wc * 64 + (l & 15);
#pragma unroll
  for (int mi = 0; mi < 4; ++mi) {
#pragma unroll
    for (int ni = 0; ni < 4; ++ni) {
#pragma unroll
      for (int j = 0; j < 4; ++j) {
        const int row = rbase + mi * 16 + j;
        const int col = cbase + ni * 16;
        const float v = acc[mi][ni][j];
        if (EP == EP_BF16) {
          ((u16*)Cv)[(long)z * sCz + (long)row * ldc + col] = f2bf(v);
        } else if (EP == EP_PV) {
          if (col < 42) {  // n0 == 0 here; col is within-head dim
            const float iv = aux[z * 1024 + row];
            ((u16*)Cv)[(long)row * ldc + z * 42 + col] = f2bf(v * iv);
          }
        } else if (EP == EP_F32B) {
          ((float*)Cv)[(long)row * ldc + col] = v + bias[col];
        } else if (EP == EP_GELU) {
          const float t = v + bias[col];
          const float g = 0.5f * t * (1.0f + erff(t * 0.70710678118654752f));
          ((u16*)Cv)[(long)row * ldc + col] = f2bf(g);
        } else {  // EP_OUT
          ((float*)Cv)[(long)row * ldc + col] =
              v + bias[col] + aux[(long)row * ldc + col];
        }
      }
    }
  }
}

// ---------------------------------------------------------------------------
// LayerNorm kernels (one 256-thread block per row of 512)
// ---------------------------------------------------------------------------
__global__ void ln1_kernel(const float* __restrict__ x,
                           const float* __restrict__ gamma,
                           const float* __restrict__ beta,
                           u16* __restrict__ n1) {
  __shared__ float red[16];
  const int s = blockIdx.x;
  const int t = threadIdx.x;
  const float* row = x + (long)s * 512;
  const float v0 = row[t];
  const float v1 = row[t + 256];
  float sum = wred_sum(v0 + v1);
  float sq = wred_sum(v0 * v0 + v1 * v1);
  if ((t & 63) == 0) { red[t >> 6] = sum; red[8 + (t >> 6)] = sq; }
  __syncthreads();
  sum = red[0] + red[1] + red[2] + red[3];
  sq = red[8] + red[9] + red[10] + red[11];
  const float mu = sum * (1.0f / 512.0f);
  const float rstd = rsqrtf(sq * (1.0f / 512.0f) - mu * mu + 1e-5f);
  n1[(long)s * 512 + t] = f2bf((v0 - mu) * rstd * gamma[t] + beta[t]);
  n1[(long)s * 512 + t + 256] =
      f2bf((v1 - mu) * rstd * gamma[t + 256] + beta[t + 256]);
}

// first_added = attn_proj[s] + x[b,s]; writes fa (f32) and n2 (bf16)
__global__ void ln2_kernel(const float* __restrict__ x,
                           const float* __restrict__ aproj,
                           const float* __restrict__ gamma,
                           const float* __restrict__ beta,
                           float* __restrict__ fa, u16* __restrict__ n2) {
  __shared__ float red[16];
  const int r = blockIdx.x;  // b*1024 + s
  const int t = threadIdx.x;
  const int s = r & 1023;
  const float* xr = x + (long)r * 512;
  const float* ar = aproj + (long)s * 512;
  const float v0 = xr[t] + ar[t];
  const float v1 = xr[t + 256] + ar[t + 256];
  fa[(long)r * 512 + t] = v0;
  fa[(long)r * 512 + t + 256] = v1;
  float sum = wred_sum(v0 + v1);
  float sq = wred_sum(v0 * v0 + v1 * v1);
  if ((t & 63) == 0) { red[t >> 6] = sum; red[8 + (t >> 6)] = sq; }
  __syncthreads();
  sum = red[0] + red[1] + red[2] + red[3];
  sq = red[8] + red[9] + red[10] + red[11];
  const float mu = sum * (1.0f / 512.0f);
  const float rstd = rsqrtf(sq * (1.0f / 512.0f) - mu * mu + 1e-5f);
  n2[(long)r * 512 + t] = f2bf((v0 - mu) * rstd * gamma[t] + beta[t]);
  n2[(long)r * 512 + t + 256] =
      f2bf((v1 - mu) * rstd * gamma[t + 256] + beta[t + 256]);
}

// in-place row softmax over bf16 scores [12*1024][1024]; stores 1/sum
__global__ void softmax_kernel(u16* __restrict__ SP, float* __restrict__ invl) {
  __shared__ float red[16];
  const long row = blockIdx.x;
  u16* p = SP + row * 1024;
  const int t = threadIdx.x;
  uint2 u = ((const uint2*)p)[t];
  const float s0 = bf2f((u16)(u.x & 0xffff));
  const float s1 = bf2f((u16)(u.x >> 16));
  const float s2 = bf2f((u16)(u.y & 0xffff));
  const float s3 = bf2f((u16)(u.y >> 16));
  float m = wred_max(fmaxf(fmaxf(s0, s1), fmaxf(s2, s3)));
  if ((t & 63) == 0) red[t >> 6] = m;
  __syncthreads();
  m = fmaxf(fmaxf(red[0], red[1]), fmaxf(red[2], red[3]));
  const float e0 = __expf(s0 - m), e1 = __expf(s1 - m);
  const float e2 = __expf(s2 - m), e3 = __expf(s3 - m);
  float sum = wred_sum(e0 + e1 + e2 + e3);
  if ((t & 63) == 0) red[8 + (t >> 6)] = sum;
  __syncthreads();
  sum = red[8] + red[9] + red[10] + red[11];
  if (t == 0) invl[row] = 1.0f / sum;
  uint2 o;
  o.x = (unsigned)f2bf(e0) | ((unsigned)f2bf(e1) << 16);
  o.y = (unsigned)f2bf(e2) | ((unsigned)f2bf(e3) << 16);
  ((uint2*)p)[t] = o;
}

// ---------------------------------------------------------------------------
// weight re-layout prep kernels (run every call; ~8MB total, cheap)
// ---------------------------------------------------------------------------
// BtQKV [1536][512]: row n -> (p=n/768, h=(n%768)/64, e=n%64); q pre-scaled
__global__ void prep_qkv_kernel(const float* __restrict__ wq,
                                const float* __restrict__ wk,
                                u16* __restrict__ BtQKV, float scale) {
  const int i = blockIdx.x * 256 + threadIdx.x;
  const int n = i >> 9, d = i & 511;
  const int pq = n / 768;
  const int h = (n % 768) >> 6;
  const int e = n & 63;
  float v = 0.f;
  if (e < 42) {
    v = (pq ? wk : wq)[((long)h * 512 + d) * 42 + e];
    if (!pq) v *= scale;
  }
  BtQKV[i] = f2bf(v);
}
// wvT [12][128][512]: row r=(h*128+e): wv[h][d][e], zero-padded e>=42
__global__ void prep_wvT_kernel(const float* __restrict__ wv,
                                u16* __restrict__ wvT) {
  const int i = blockIdx.x * 256 + threadIdx.x;
  const int r = i >> 9, d = i & 511;
  const int h = r >> 7, e = r & 127;
  wvT[i] = f2bf(e < 42 ? wv[((long)h * 512 + d) * 42 + e] : 0.f);
}
// BtP [512][512]: w_proj^T, K padded 504->512 with zeros
__global__ void prep_proj_kernel(const float* __restrict__ wp,
                                 u16* __restrict__ BtP) {
  const int i = blockIdx.x * 256 + threadIdx.x;
  const int n = i >> 9, k = i & 511;
  BtP[i] = f2bf(k < 504 ? wp[(long)k * 512 + n] : 0.f);
}
__global__ void prep_w1_kernel(const float* __restrict__ w1,
                               u16* __restrict__ Bt1) {
  const int i = blockIdx.x * 256 + threadIdx.x;  // [2048][512]
  const int n = i >> 9, k = i & 511;
  Bt1[i] = f2bf(w1[(long)k * 2048 + n]);
}
__global__ void prep_w2_kernel(const float* __restrict__ w2,
                               u16* __restrict__ Bt2) {
  const int i = blockIdx.x * 256 + threadIdx.x;  // [512][2048]
  const int n = i >> 11, k = i & 2047;
  Bt2[i] = f2bf(w2[(long)k * 512 + n]);
}
__global__ void zero_u16_kernel(u16* __restrict__ p) {
  p[blockIdx.x * 256 + threadIdx.x] = 0;
}

// ---------------------------------------------------------------------------
extern "C" void kernel_launch(void* const* d_in, const int* in_sizes, int n_in,
                              void* d_out, int out_size, void* d_ws,
                              size_t ws_size, hipStream_t stream) {
  const float* x = (const float*)d_in[0];
  const float* wk = (const float*)d_in[1];   // NOTE: wk before wq in dict order
  const float* wq = (const float*)d_in[2];
  const float* wv = (const float*)d_in[3];
  const float* w_proj = (const float*)d_in[4];
  const float* b_proj = (const float*)d_in[5];
  const float* gamma = (const float*)d_in[6];
  const float* beta = (const float*)d_in[7];
  const float* w1 = (const float*)d_in[8];
  const float* b1 = (const float*)d_in[9];
  const float* w2 = (const float*)d_in[10];
  const float* b2 = (const float*)d_in[11];

  char* base = (char*)d_ws;
  size_t off = 0;
  auto alloc = [&](size_t bytes) -> void* {
    void* p = base + off;
    off += (bytes + 255) & ~(size_t)255;
    return p;
  };
  u16* n1 = (u16*)alloc(1024L * 512 * 2);        // LN1(x[0]) bf16
  u16* qkvc = (u16*)alloc(1024L * 1536 * 2);     // [s][(q|k) h e64] bf16
  u16* SP = (u16*)alloc(12L * 1024 * 1024 * 2);  // scores -> P, bf16, in-place
  u16* wvT = (u16*)alloc(1536L * 512 * 2);       // [h*128+e][d]
  u16* vt = (u16*)alloc(1536L * 1024 * 2);       // v^T [h*128+e][t]
  u16* cat = (u16*)alloc(1024L * 512 * 2);       // concat heads, pad 504->512
  float* aproj = (float*)alloc(1024L * 512 * 4); // attn @ w_proj + b_proj
  float* fa = (float*)alloc(8192L * 512 * 4);    // first_added, f32
  u16* n2 = (u16*)alloc(8192L * 512 * 2);        // LN2 bf16
  u16* hbuf = (u16*)alloc(8192L * 2048 * 2);     // gelu(mlp1) bf16
  u16* BtQKV = (u16*)alloc(1536L * 512 * 2);
  u16* BtP = (u16*)alloc(512L * 512 * 2);
  u16* Bt1 = (u16*)alloc(2048L * 512 * 2);
  u16* Bt2 = (u16*)alloc(512L * 2048 * 2);
  float* invl = (float*)alloc(12L * 1024 * 4);
  (void)ws_size; (void)in_sizes; (void)n_in; (void)out_size;

  const float scale = 0.15430334996209191f;  // 42^-0.5 folded into q weights

  prep_qkv_kernel<<<3072, 256, 0, stream>>>(wq, wk, BtQKV, scale);
  prep_wvT_kernel<<<3072, 256, 0, stream>>>(wv, wvT);
  prep_proj_kernel<<<1024, 256, 0, stream>>>(w_proj, BtP);
  prep_w1_kernel<<<4096, 256, 0, stream>>>(w1, Bt1);
  prep_w2_kernel<<<4096, 256, 0, stream>>>(w2, Bt2);
  zero_u16_kernel<<<2048, 256, 0, stream>>>(cat);
  ln1_kernel<<<1024, 256, 0, stream>>>(x, gamma, beta, n1);

  // q,k = n1 @ {wq*scale, wk}: [1024,1536], K=512
  gemm_bt<EP_BF16><<<dim3(8, 12, 1), 256, 0, stream>>>(
      n1, 512, 0, BtQKV, 512, 0, qkvc, 1536, 0, 512, nullptr, nullptr);
  // vt = wvT @ n1^T: [1536,1024], K=512
  gemm_bt<EP_BF16><<<dim3(12, 8, 1), 256, 0, stream>>>(
      wvT, 512, 0, n1, 512, 0, vt, 1024, 0, 512, nullptr, nullptr);
  // scores per head: q_h [1024,64] x k_h^T -> [1024,1024] bf16
  gemm_bt<EP_BF16><<<dim3(8, 8, 12), 256, 0, stream>>>(
      qkvc, 1536, 64, qkvc + 768, 1536, 64, SP, 1024, 1024L * 1024, 64,
      nullptr, nullptr);
  softmax_kernel<<<12288, 256, 0, stream>>>(SP, invl);
  // out_h = P_h @ v_h: [1024,128], keep cols<42, /l, scatter into concat
  gemm_bt<EP_PV><<<dim3(8, 1, 12), 256, 0, stream>>>(
      SP, 1024, 1024L * 1024, vt, 1024, 128L * 1024, cat, 512, 0, 1024,
      nullptr, invl);
  // attn_proj = concat @ w_proj + b_proj: [1024,512] f32
  gemm_bt<EP_F32B><<<dim3(8, 4, 1), 256, 0, stream>>>(
      cat, 512, 0, BtP, 512, 0, aproj, 512, 0, 512, b_proj, nullptr);
  ln2_kernel<<<8192, 256, 0, stream>>>(x, aproj, gamma, beta, fa, n2);
  // h = gelu(n2 @ w1 + b1): [8192,2048] bf16
  gemm_bt<EP_GELU><<<dim3(64, 16, 1), 256, 0, stream>>>(
      n2, 512, 0, Bt1, 512, 0, hbuf, 2048, 0, 512, b1, nullptr);
  // out = h @ w2 + b2 + fa: [8192,512] f32
  gemm_bt<EP_OUT><<<dim3(64, 4, 1), 256, 0, stream>>>(
      hbuf, 2048, 0, Bt2, 2048, 0, d_out, 512, 0, 2048, b2, fa);
}